// Round 10
// baseline (178.788 us; speedup 1.0000x reference)
//
#include <hip/hip_runtime.h>
#include <math.h>

// Problem constants
#define T_DIM 8192
#define N_DIM 4096
#define L 64
#define P 32
#define IN_DIM 192
#define S_CHUNK 16
#define N_CHUNK (T_DIM / S_CHUNK)   // 512
#define LDST 68                     // padded LDS row stride (float4-aligned)

using f32x4   = __attribute__((ext_vector_type(4))) float;
using bf16x8  = __attribute__((ext_vector_type(8))) short;
using ushort8 = __attribute__((ext_vector_type(8))) unsigned short;

__device__ __forceinline__ unsigned short f2bf(float x) {
  unsigned u = __float_as_uint(x);
  u += 0x7fffu + ((u >> 16) & 1u);           // round-to-nearest-even
  return (unsigned short)(u >> 16);
}
__device__ __forceinline__ float bf2f(unsigned short h) {
  return __uint_as_float(((unsigned)h) << 16);
}

// Packed fragment layout (both X and U):
//   pk[tile16][g][lane] = 8 bf16 of row (tile16*16 + lane), k-chunk g
//   g in 0..15: g<8 -> hi bits of k=8g..; g>=8 -> lo residual.
__device__ __forceinline__ bf16x8 ldfrag(const unsigned short* __restrict__ base,
                                         int tile16, int gb, int lg, int lr) {
  return *(const bf16x8*)(base + ((size_t)((tile16 * 16 + gb + lg) * 16 + lr)) * 8);
}

// ---------------- kernel A (merged): xh0 partials + U split + scratch init ----------------
__global__ __launch_bounds__(256) void k_init(const float* __restrict__ U,
                                              const float* __restrict__ Xtr,
                                              float* __restrict__ part,
                                              double* __restrict__ acc,
                                              int* __restrict__ cnt,
                                              unsigned short* __restrict__ upk) {
  int blk = blockIdx.x, tid = threadIdx.x;
  if (blk < 16) {
    if (blk == 0) {
      if (tid < 2) acc[tid] = 0.0;
      if (tid == 2) *cnt = 0;
    }
    int b = blk * 4 + (tid >> 6);
    int l = tid & 63;
    int n0 = b * 64;
    float s = 0.f;
    #pragma unroll 8
    for (int i = 0; i < 64; ++i) {
      float x = Xtr[n0 + i];
      s += U[(size_t)(n0 + i) * L + l] * x;
    }
    part[b * 64 + l] = s;
  } else {
    int idx = (blk - 16) * 256 + tid;         // 0 .. 65535
    int lr = idx & 15, g = (idx >> 4) & 15, nn16 = idx >> 8;
    int n = nn16 * 16 + lr;
    int k0 = (g & 7) * 8;
    float4 a = *(const float4*)(U + (size_t)n * L + k0);
    float4 b = *(const float4*)(U + (size_t)n * L + k0 + 4);
    ushort8 o;
    float v[8] = {a.x, a.y, a.z, a.w, b.x, b.y, b.z, b.w};
    #pragma unroll
    for (int j = 0; j < 8; ++j) {
      unsigned short h = f2bf(v[j]);
      o[j] = (g < 8) ? h : f2bf(v[j] - bf2f(h));
    }
    *(ushort8*)(upk + (size_t)idx * 8) = o;
  }
}

// ---------------- kernel B: argmax, temp, build M, xh0, matrix doublings ----------------
__global__ __launch_bounds__(256, 1) void k_prep(const float* __restrict__ A_tilde,
                                                 const float* __restrict__ phi_bar_t,
                                                 const float* __restrict__ logits,
                                                 const float* __restrict__ temp,
                                                 const float* __restrict__ part,
                                                 float* __restrict__ Wm,
                                                 float* __restrict__ xh0,
                                                 float* __restrict__ out_tail) {
  __shared__ float buf[2][64 * LDST];   // 34816 B
  __shared__ float sphi[P * L];         // 8192 B
  __shared__ float spart[4 * 64];       // 1024 B
  __shared__ int   sel_s[P];
  int tid = threadIdx.x;

  #pragma unroll
  for (int i = 0; i < 4; ++i) {
    int f = tid + 256 * i;
    int r = f >> 4, q = f & 15;
    float4 v = ((const float4*)A_tilde)[f];
    *(float4*)(buf[0] + r * LDST + q * 4) = v;
  }
  #pragma unroll
  for (int i = 0; i < 2; ++i) {
    int f = tid + 256 * i;
    ((float4*)sphi)[f] = ((const float4*)phi_bar_t)[f];
  }
  {
    int l = tid & 63, q = tid >> 6;
    float s = 0.f;
    #pragma unroll
    for (int i = 0; i < 16; ++i)
      s += part[(q * 16 + i) * 64 + l];
    spart[q * 64 + l] = s;
  }
  {
    int p = tid >> 3, d = tid & 7;
    const float* row = logits + p * IN_DIM;
    float best = -1e30f; int bk = 0;
    #pragma unroll
    for (int j = 0; j < 6; ++j) {
      int kb = (j * 8 + d) * 4;
      float4 v = *(const float4*)(row + kb);
      if (v.x > best) { best = v.x; bk = kb; }
      if (v.y > best) { best = v.y; bk = kb + 1; }
      if (v.z > best) { best = v.z; bk = kb + 2; }
      if (v.w > best) { best = v.w; bk = kb + 3; }
    }
    #pragma unroll
    for (int off = 4; off > 0; off >>= 1) {
      float vo = __shfl_down(best, off, 8);
      int   ko = __shfl_down(bk,   off, 8);
      if (vo > best || (vo == best && ko < bk)) { best = vo; bk = ko; }
    }
    if (d == 0) {
      sel_s[p] = bk;
      out_tail[2 + p] = (float)bk;
    }
  }
  if (tid == 255) out_tail[1] = fmaxf(0.01f, temp[0] * 0.999f);
  __syncthreads();

  if (tid < L) {
    #pragma unroll 4
    for (int p = 0; p < P; ++p) {
      int kk = sel_s[p]; if (kk > L - 1) kk = L - 1;
      buf[0][tid * LDST + kk] += sphi[p * L + tid];
    }
  } else if (tid < 128) {
    int l = tid - 64;
    xh0[l] = spart[l] + spart[64 + l] + spart[128 + l] + spart[192 + l];
  }
  __syncthreads();

  #pragma unroll
  for (int i = 0; i < 4; ++i) {
    int f = tid + 256 * i;
    int r = f >> 4, q = f & 15;
    *(float4*)(Wm + r * 64 + q * 4) = *(const float4*)(buf[0] + r * LDST + q * 4);
  }

  int r0 = (tid >> 4) << 2;
  int c0 = (tid & 15) << 2;
  int cur = 0;
  for (int j = 1; j <= 12; ++j) {
    const float* S = buf[cur];
    float* D = buf[cur ^ 1];
    float acc[4][4];
    #pragma unroll
    for (int i = 0; i < 4; ++i)
      #pragma unroll
      for (int c = 0; c < 4; ++c) acc[i][c] = 0.f;

    #pragma unroll
    for (int kb = 0; kb < 64; kb += 16) {
      float a[4][16];
      #pragma unroll
      for (int i = 0; i < 4; ++i)
        #pragma unroll
        for (int q = 0; q < 4; ++q) {
          float4 t4 = *(const float4*)(S + (r0 + i) * LDST + kb + q * 4);
          a[i][q * 4 + 0] = t4.x; a[i][q * 4 + 1] = t4.y;
          a[i][q * 4 + 2] = t4.z; a[i][q * 4 + 3] = t4.w;
        }
      #pragma unroll
      for (int kk = 0; kk < 16; ++kk) {
        float4 b4 = *(const float4*)(S + (kb + kk) * LDST + c0);
        #pragma unroll
        for (int i = 0; i < 4; ++i) {
          acc[i][0] += a[i][kk] * b4.x;
          acc[i][1] += a[i][kk] * b4.y;
          acc[i][2] += a[i][kk] * b4.z;
          acc[i][3] += a[i][kk] * b4.w;
        }
      }
    }
    #pragma unroll
    for (int i = 0; i < 4; ++i) {
      float4 o = {acc[i][0], acc[i][1], acc[i][2], acc[i][3]};
      *(float4*)(D + (r0 + i) * LDST + c0) = o;
      *(float4*)(Wm + j * 4096 + (r0 + i) * 64 + c0) = o;
    }
    __syncthreads();
    cur ^= 1;
  }
}

// ---------------- kernel C: states via checkpoints; emit PACKED bf16 hi/lo frags ----------------
__global__ __launch_bounds__(64) void k_states(const float* __restrict__ Wm,
                                               const float* __restrict__ xh0,
                                               unsigned short* __restrict__ xpk) {
  __shared__ float sx[16 * LDST];
  int c = blockIdx.x;
  int l = threadIdx.x;
  float v = xh0[l];
  int e = c << 4;
  for (int j = 4; j <= 12; ++j) {
    if ((e >> j) & 1) {
      const float* W = Wm + j * 4096;
      float n0 = 0.f, n1 = 0.f, n2 = 0.f, n3 = 0.f;
      #pragma unroll
      for (int k = 0; k < 64; k += 4) {
        n0 += W[l * 64 + k]     * __shfl(v, k, 64);
        n1 += W[l * 64 + k + 1] * __shfl(v, k + 1, 64);
        n2 += W[l * 64 + k + 2] * __shfl(v, k + 2, 64);
        n3 += W[l * 64 + k + 3] * __shfl(v, k + 3, 64);
      }
      v = (n0 + n1) + (n2 + n3);
    }
  }
  float m[64];
  #pragma unroll
  for (int k = 0; k < 64; ++k) m[k] = Wm[l * 64 + k];
  for (int i = 0; i < S_CHUNK; ++i) {
    float n0 = 0.f, n1 = 0.f, n2 = 0.f, n3 = 0.f;
    #pragma unroll
    for (int k = 0; k < 64; k += 4) {
      n0 += m[k]     * __shfl(v, k, 64);
      n1 += m[k + 1] * __shfl(v, k + 1, 64);
      n2 += m[k + 2] * __shfl(v, k + 2, 64);
      n3 += m[k + 3] * __shfl(v, k + 3, 64);
    }
    v = (n0 + n1) + (n2 + n3);
    sx[i * LDST + l] = v;
  }
  __syncthreads();

  #pragma unroll
  for (int it = 0; it < 4; ++it) {
    int idx = l + 64 * it;
    int lr = idx & 15, g = idx >> 4;
    int k0 = (g & 7) * 8;
    float4 a = *(const float4*)(sx + lr * LDST + k0);
    float4 b = *(const float4*)(sx + lr * LDST + k0 + 4);
    float vv[8] = {a.x, a.y, a.z, a.w, b.x, b.y, b.z, b.w};
    ushort8 o;
    #pragma unroll
    for (int j = 0; j < 8; ++j) {
      unsigned short h = f2bf(vv[j]);
      o[j] = (g < 8) ? h : f2bf(vv[j] - bf2f(h));
    }
    *(ushort8*)(xpk + ((size_t)c * 256 + idx) * 8) = o;
  }
}

// ---------------- kernel D: streaming MFMA GEMM, register ping-pong pipeline ----------------
// 1024 blocks x (16 t-rows x 2048 n), n swept sequentially (contiguous Y/Xrec
// spans). Round-9 failure: rolled loop -> compiler sank ldfrags to uses
// (VGPR=32, serialized L2 chain, 164 us). Fix: explicit 2-stage register
// ping-pong (u0/u1, y pairs), fully unrolled, all static indices -> next
// iteration's 8 frag loads + 2 Y loads issue before current MFMAs, ~120 VGPR.
#define MFMA(A, B, C) __builtin_amdgcn_mfma_f32_16x16x32_bf16(A, B, C, 0, 0, 0)

__global__ __launch_bounds__(256) void k_xrec(const unsigned short* __restrict__ xpk,
                                              const unsigned short* __restrict__ upk,
                                              const float* __restrict__ Y,
                                              float* __restrict__ Xrec,
                                              double* __restrict__ acc_g,
                                              int* __restrict__ cnt,
                                              float* __restrict__ out_tail) {
  __shared__ float red[512];
  int tid = threadIdx.x;
  int raw = blockIdx.x;                    // 1024 wgs, 8 XCDs, 128/XCD
  int wg = (raw & 7) * 128 + (raw >> 3);   // bijective chunked swizzle
  int th = wg >> 1;                        // t-stripe 0..511
  int nh = wg & 1;                         // n half
  int l = tid & 63, w = tid >> 6;
  int lr = l & 15, lg = l >> 4;
  int nwb = nh * 2048 + w * 512;           // wave n base
  int nf = nwb >> 4;                       // u tile16 base; iter g uses nf+2g, nf+2g+1

  // persistent X frags (tile16 == th)
  bf16x8 a_hi0 = ldfrag(xpk, th, 0,  lg, lr);
  bf16x8 a_hi1 = ldfrag(xpk, th, 4,  lg, lr);
  bf16x8 a_lo0 = ldfrag(xpk, th, 8,  lg, lr);
  bf16x8 a_lo1 = ldfrag(xpk, th, 12, lg, lr);

  int t = th * 16 + lr;
  size_t base0 = (size_t)t * N_DIM + nwb + lg * 4;  // iter g: base0 + g*32 (+16 for acc1)

  float sd = 0.f, sy = 0.f;

#define LDU8(arr, b_) do { \
    arr##0 = ldfrag(upk, (b_),     0,  lg, lr); \
    arr##1 = ldfrag(upk, (b_),     4,  lg, lr); \
    arr##2 = ldfrag(upk, (b_),     8,  lg, lr); \
    arr##3 = ldfrag(upk, (b_),     12, lg, lr); \
    arr##4 = ldfrag(upk, (b_) + 1, 0,  lg, lr); \
    arr##5 = ldfrag(upk, (b_) + 1, 4,  lg, lr); \
    arr##6 = ldfrag(upk, (b_) + 1, 8,  lg, lr); \
    arr##7 = ldfrag(upk, (b_) + 1, 12, lg, lr); \
  } while (0)

#define STEP(arr, yA, yB, g_) do { \
    f32x4 ac0 = (f32x4){0.f, 0.f, 0.f, 0.f}; \
    f32x4 ac1 = (f32x4){0.f, 0.f, 0.f, 0.f}; \
    ac0 = MFMA(arr##0, a_hi0, ac0);  ac1 = MFMA(arr##4, a_hi0, ac1); \
    ac0 = MFMA(arr##1, a_hi1, ac0);  ac1 = MFMA(arr##5, a_hi1, ac1); \
    ac0 = MFMA(arr##0, a_lo0, ac0);  ac1 = MFMA(arr##4, a_lo0, ac1); \
    ac0 = MFMA(arr##1, a_lo1, ac0);  ac1 = MFMA(arr##5, a_lo1, ac1); \
    ac0 = MFMA(arr##2, a_hi0, ac0);  ac1 = MFMA(arr##6, a_hi0, ac1); \
    ac0 = MFMA(arr##3, a_hi1, ac0);  ac1 = MFMA(arr##7, a_hi1, ac1); \
    size_t idx = base0 + (g_) * 32; \
    float d; \
    d = yA.x - ac0[0]; sd += d * d; sy += yA.x * yA.x; \
    d = yA.y - ac0[1]; sd += d * d; sy += yA.y * yA.y; \
    d = yA.z - ac0[2]; sd += d * d; sy += yA.z * yA.z; \
    d = yA.w - ac0[3]; sd += d * d; sy += yA.w * yA.w; \
    d = yB.x - ac1[0]; sd += d * d; sy += yB.x * yB.x; \
    d = yB.y - ac1[1]; sd += d * d; sy += yB.y * yB.y; \
    d = yB.z - ac1[2]; sd += d * d; sy += yB.z * yB.z; \
    d = yB.w - ac1[3]; sd += d * d; sy += yB.w * yB.w; \
    *(f32x4*)(Xrec + idx) = ac0; \
    *(f32x4*)(Xrec + idx + 16) = ac1; \
  } while (0)

  bf16x8 p0, p1, p2, p3, p4, p5, p6, p7;
  bf16x8 q0, q1, q2, q3, q4, q5, q6, q7;
  float4 py0, py1, qy0, qy1;

  LDU8(p, nf);
  py0 = *(const float4*)(Y + base0);
  py1 = *(const float4*)(Y + base0 + 16);

  #pragma unroll
  for (int gg = 0; gg < 8; ++gg) {
    int g0 = 2 * gg, g1 = g0 + 1;
    // prefetch odd iteration's operands before consuming even
    LDU8(q, nf + 2 * g1);
    qy0 = *(const float4*)(Y + base0 + g1 * 32);
    qy1 = *(const float4*)(Y + base0 + g1 * 32 + 16);
    STEP(p, py0, py1, g0);
    if (gg < 7) {
      LDU8(p, nf + 2 * (g0 + 2));
      py0 = *(const float4*)(Y + base0 + (g0 + 2) * 32);
      py1 = *(const float4*)(Y + base0 + (g0 + 2) * 32 + 16);
    }
    STEP(q, qy0, qy1, g1);
  }

  red[tid] = sd; red[256 + tid] = sy;
  __syncthreads();
  for (int s2 = 128; s2 > 0; s2 >>= 1) {
    if (tid < s2) { red[tid] += red[tid + s2]; red[256 + tid] += red[256 + tid + s2]; }
    __syncthreads();
  }
  if (tid == 0) {
    atomicAdd(acc_g,     (double)red[0]);
    atomicAdd(acc_g + 1, (double)red[256]);
    __threadfence();
    int done = atomicAdd(cnt, 1);
    if (done == 1023) {                       // last block finalizes err
      double s0 = atomicAdd(acc_g, 0.0);
      double s1 = atomicAdd(acc_g + 1, 0.0);
      out_tail[0] = (float)sqrt(s0 / s1);
    }
  }
}

extern "C" void kernel_launch(void* const* d_in, const int* in_sizes, int n_in,
                              void* d_out, int out_size, void* d_ws, size_t ws_size,
                              hipStream_t stream) {
  const float* X_train = (const float*)d_in[1];
  const float* Y       = (const float*)d_in[2];
  const float* temp    = (const float*)d_in[3];
  const float* phi     = (const float*)d_in[4];
  const float* A_tilde = (const float*)d_in[5];
  const float* U       = (const float*)d_in[6];
  const float* logits  = (const float*)d_in[7];
  float* out = (float*)d_out;
  float* out_tail = out + (size_t)T_DIM * N_DIM;

  // workspace layout (bytes)
  char* w = (char*)d_ws;
  double* acc          = (double*)w;                     // @0, 16 B
  int* cnt             = (int*)(w + 32);                 // 4 B
  float* Wm            = (float*)(w + 64);               // 13*16384 B -> ends 213056
  float* xh0           = (float*)(w + 213056);           // 256 B
  float* part          = (float*)(w + 213312);           // 16384 B -> ends 229696
  unsigned short* upk  = (unsigned short*)(w + 262144);  // 1 MiB packed U frags
  unsigned short* xpk  = (unsigned short*)(w + 1310720); // 2 MiB packed X frags -> ends 3407872

  k_init<<<272, 256, 0, stream>>>(U, X_train, part, acc, cnt, upk);
  k_prep<<<1, 256, 0, stream>>>(A_tilde, phi, logits, temp, part, Wm, xh0, out_tail);
  k_states<<<N_CHUNK, 64, 0, stream>>>(Wm, xh0, xpk);
  k_xrec<<<1024, 256, 0, stream>>>(xpk, upk, Y, out, acc, cnt, out_tail);
}